// Round 1
// baseline (383.779 us; speedup 1.0000x reference)
//
#include <hip/hip_runtime.h>

// CTC loss forward (reduction='none', zero_infinity=True), matching the JAX ref.
// Shapes (fixed by setup_inputs): log_probs (T,N,C)=(512,512,80) fp32,
// targets (N,S)=(512,128) i32, input_lengths (N,), target_lengths (N,).
// Output: (N,) fp32.
//
// Mapping: one block per batch element n; thread s handles lattice position
// s (thread 0 also handles s=256). Alpha recursion over t is sequential;
// ping-pong alpha buffers in LDS + distance-2 register prefetch of the
// 80-float prob row give exactly ONE __syncthreads per timestep.

#define NEGC (-1.0e30f)

constexpr int T_ = 512;
constexpr int C_ = 80;
constexpr int S_ = 128;
constexpr int L_ = 2 * S_ + 1;  // 257

__global__ __launch_bounds__(256) void ctc_fwd(
    const float* __restrict__ lp,    // (T,N,C)
    const int*   __restrict__ tgt,   // (N,S)
    const int*   __restrict__ ilen,  // (N)
    const int*   __restrict__ tlen,  // (N)
    float*       __restrict__ out,   // (N)
    int N)
{
    const int n   = blockIdx.x;
    const int tid = threadIdx.x;

    __shared__ float pb[2][C_];      // staged prob rows, alternating on t&1
    __shared__ float ap[2][L_ + 2];  // ping-pong alpha, 2 leading NEG pads

    // Extended label + skip flag for s = tid.
    // ext[s] = 0 (blank) for even s, targets[(s-1)/2] for odd s.
    // skip_ok[s] = s>=2 && ext[s] != ext[s-2]  (false for all blanks).
    int  ext0  = 0;
    bool skip0 = false;
    if (tid & 1) {
        const int k = tid >> 1;
        ext0 = tgt[n * S_ + k];
        if (tid >= 3) skip0 = (ext0 != tgt[n * S_ + k - 1]);
    }

    int len = ilen[n];
    len = len < 1 ? 1 : (len > T_ ? T_ : len);   // loop can stop at len: alpha frozen after

    const int f4stride = N * C_ / 4;                       // float4 per timestep
    const float4* lp4 = (const float4*)(lp + (size_t)n * C_);
    const bool loader = (tid < C_ / 4);                    // 20 loader lanes

    float4 ld;
    if (loader) ld = lp4[tid];                             // t = 0

    if (tid < 2) { ap[0][tid] = NEGC; ap[1][tid] = NEGC; } // pads, never overwritten

    if (loader) ((float4*)pb[0])[tid] = ld;
    __syncthreads();

    // alpha0: only s=0 (blank) and s=1 (first label) reachable
    float a0 = NEGC;
    if      (tid == 0) a0 = pb[0][0];
    else if (tid == 1) a0 = pb[0][ext0];
    ap[0][2 + tid] = a0;
    if (tid == 0) ap[0][2 + 256] = NEGC;

    if (loader) {
        ld = lp4[f4stride + tid];                          // t = 1
        ((float4*)pb[1])[tid] = ld;
        if (2 < len) ld = lp4[2 * (size_t)f4stride + tid]; // t = 2 in flight
    }
    __syncthreads();

    int par = 0;
    for (int t = 1; t < len; ++t) {
        const float* pcur = pb[t & 1];     // probs for t: staged 1 iter ago, behind barrier
        const float* ar   = ap[par];
        float*       aw   = ap[par ^ 1];

        const float a  = ar[2 + tid];
        const float a1 = ar[1 + tid];
        const float a2 = skip0 ? ar[tid] : NEGC;

        const float m   = fmaxf(a, fmaxf(a1, a2));
        const float lse = m + __logf(__expf(a - m) + __expf(a1 - m) + __expf(a2 - m));
        aw[2 + tid] = lse + pcur[ext0];

        if (tid == 0) {                    // second position s = 256 (blank, no skip)
            const float b  = ar[2 + 256];
            const float b1 = ar[1 + 256];
            const float mb = fmaxf(b, b1);
            aw[2 + 256] = mb + __logf(__expf(b - mb) + __expf(b1 - mb)) + pcur[0];
        }

        if (loader) {
            ((float4*)pb[(t + 1) & 1])[tid] = ld;          // stage probs for t+1
            if (t + 2 < len) ld = lp4[(size_t)(t + 2) * f4stride + tid]; // prefetch t+2
        }
        __syncthreads();
        par ^= 1;
    }

    if (tid == 0) {
        const int tl = tlen[n];
        const int i1 = 2 * tl;                             // <= 256
        const float v1 = ap[par][2 + i1];
        const float v2 = ap[par][2 + i1 - 1];
        const float m  = fmaxf(v1, v2);
        float loss = -(m + __logf(__expf(v1 - m) + __expf(v2 - m)));
        // zero_infinity: infeasible -> 0. !(x<1e10) also catches NaN.
        if (!(loss < 1e10f) || !isfinite(loss)) loss = 0.0f;
        out[n] = loss;
    }
}

extern "C" void kernel_launch(void* const* d_in, const int* in_sizes, int n_in,
                              void* d_out, int out_size, void* d_ws, size_t ws_size,
                              hipStream_t stream) {
    const float* lp   = (const float*)d_in[0];
    const int*   tgt  = (const int*)  d_in[1];
    const int*   il   = (const int*)  d_in[2];
    const int*   tl   = (const int*)  d_in[3];
    float*       out  = (float*)d_out;
    const int N = in_sizes[2];           // 512
    ctc_fwd<<<N, 256, 0, stream>>>(lp, tgt, il, tl, out, N);
}

// Round 2
// 207.376 us; speedup vs baseline: 1.8506x; 1.8506x over previous
//
#include <hip/hip_runtime.h>

// CTC loss forward (reduction='none', zero_infinity=True), matching the JAX ref.
// Shapes: log_probs (T,N,C)=(512,512,80) fp32, targets (N,S)=(512,128) i32,
// input_lengths (N,), target_lengths (N,). Output: (N,) fp32.
//
// R2 design: ONE WAVE per batch element, ZERO __syncthreads.
//  - lane l owns lattice positions s=4l..4l+3 (lane 63 also s=256); alphas
//    live in registers (a0..a4). Cross-lane dep is a single __shfl_up of a3
//    (even-s positions are blanks and never take the skip transition, so the
//    only cross-lane old[s-2] consumer is s=4l+1, which needs lane l-1's a3).
//  - emission rows (80 floats) stream via global_load_lds (16B x 20 lanes)
//    into a 16-deep LDS ring; ONE load issued per iteration + manual
//    s_waitcnt vmcnt(15) keeps ~15 iterations (~2000 cyc) of latency hiding
//    with an exact in-order vmcnt<->slot cadence. No barrier ever drains it.
//  - all math in log2 domain (v_exp_f32/v_log_f32 are base-2 native).

#define NEGC  (-1.0e30f)
#define LOG2E 1.4426950408889634f
#define LN2   0.6931471805599453f

constexpr int T_ = 512;
constexpr int C_ = 80;
constexpr int S_ = 128;
constexpr int D_ = 16;   // prefetch ring depth (rows)

// raw s_waitcnt: vmcnt[3:0]|[15:14], expcnt[6:4]=7 (don't care), lgkmcnt[11:8]=15
#define WAITVM(N) __builtin_amdgcn_s_waitcnt(((N) & 0xF) | ((((N) >> 4) & 3) << 14) | 0x70 | 0xF00)
#define WAIT_LGKM0 __builtin_amdgcn_s_waitcnt(0xC07F)  // lgkmcnt(0), vm/exp don't care

#define GLD16(gp, sp)                                                        \
    __builtin_amdgcn_global_load_lds(                                        \
        (const __attribute__((address_space(1))) void*)(gp),                 \
        (__attribute__((address_space(3))) void*)(sp), 16, 0, 0)

__device__ __forceinline__ float exp2a(float x) { return __builtin_amdgcn_exp2f(x); }
__device__ __forceinline__ float log2a(float x) { return __builtin_amdgcn_logf(x); }

// log-sum-exp in base-2 domain
__device__ __forceinline__ float lse2(float x, float y) {
    float m = fmaxf(x, y);
    return m + log2a(1.0f + exp2a(-fabsf(x - y)));
}
__device__ __forceinline__ float lse3(float x, float y, float z) {
    float m = fmaxf(x, fmaxf(y, z));
    return m + log2a(exp2a(x - m) + exp2a(y - m) + exp2a(z - m));
}

__global__ __launch_bounds__(64) void ctc_fwd(
    const float* __restrict__ lp,    // (T,N,C)
    const int*   __restrict__ tgt,   // (N,S)
    const int*   __restrict__ ilen,  // (N)
    const int*   __restrict__ tlen,  // (N)
    float*       __restrict__ out,   // (N)
    int N)
{
    const int n = blockIdx.x;
    const int l = threadIdx.x;       // 0..63

    __shared__ float ring[D_ * C_];  // 16 rows x 80 floats = 5 KB
    __shared__ float af[2 * S_ + 1]; // final alpha readout

    // per-lane extended labels: s=4l+1 -> tgt[2l], s=4l+3 -> tgt[2l+1]
    const int* tn = tgt + n * S_;
    const int ext1 = tn[2 * l];
    const int ext3 = tn[2 * l + 1];
    const int prev = (l > 0) ? tn[2 * l - 1] : 0;
    const bool skip1 = (l > 0) && (ext1 != prev);  // s=4l+1 >= 3 requires l>=1... (l==0: s=1, no skip)
    const bool skip3 = (ext3 != ext1);             // s=4l+3 >= 3 always

    int len = ilen[n];
    len = len < 1 ? 1 : (len > T_ ? T_ : len);     // alpha frozen for t>=len: just stop

    const float* lpn = lp + (size_t)n * C_;
    const size_t rstride = (size_t)N * C_;
    const bool loader = (l < C_ / 4);              // 20 lanes x 16 B = 320 B row

    // prologue: fill the ring with rows 0..D-1 (clamped; extras never consumed)
    for (int r = 0; r < D_; ++r) {
        int rc = r < len ? r : (len - 1);
        if (loader) GLD16(lpn + (size_t)rc * rstride + l * 4, &ring[r * C_]);
    }
    WAITVM(D_ - 1);   // oldest (row 0) resident

    // alpha0 (log2 domain): only s=0 (blank) and s=1 (first label) reachable
    float a0 = NEGC, a1 = NEGC, a2 = NEGC, a3 = NEGC, a4 = NEGC;
    if (l == 0) {
        a0 = ring[0] * LOG2E;
        a1 = ring[ext1] * LOG2E;
    }

    for (int t = 1; t < len; ++t) {
        // issue exactly ONE ring load per iteration (keeps vmcnt cadence exact)
        {
            int rr = t + D_ - 1;
            int rc = rr < len ? rr : (len - 1);
            if (loader) GLD16(lpn + (size_t)rc * rstride + l * 4,
                              &ring[(rr & (D_ - 1)) * C_]);
        }
        WAITVM(D_ - 1);  // ring loads issued = D+t; >= t+1 oldest done -> row t resident

        const float* pcur = &ring[(t & (D_ - 1)) * C_];
        const float eb = pcur[0]    * LOG2E;   // blank emission (broadcast read)
        const float e1 = pcur[ext1] * LOG2E;
        const float e3 = pcur[ext3] * LOG2E;

        float sm1 = __shfl_up(a3, 1);          // lane l-1's old alpha at s=4l-1
        if (l == 0) sm1 = NEGC;

        const float z1 = skip1 ? sm1 : NEGC;   // old[s-2] for s=4l+1
        const float z3 = skip3 ? a1  : NEGC;   // old[s-2] for s=4l+3

        const float n0 = lse2(a0, sm1)    + eb;  // s=4l   (blank)
        const float n1 = lse3(a1, a0, z1) + e1;  // s=4l+1 (label)
        const float n2 = lse2(a2, a1)     + eb;  // s=4l+2 (blank)
        const float n3 = lse3(a3, a2, z3) + e3;  // s=4l+3 (label)
        const float n4 = lse2(a4, a3)     + eb;  // s=256 (lane 63 only; junk elsewhere, unused)
        a0 = n0; a1 = n1; a2 = n2; a3 = n3; a4 = n4;
    }

    WAITVM(0);  // drain in-flight LDS-DMA before LDS reuse / endpgm

    // readout: final states 2*tl (last blank) and 2*tl-1 (last label)
    af[4 * l + 0] = a0; af[4 * l + 1] = a1;
    af[4 * l + 2] = a2; af[4 * l + 3] = a3;
    if (l == 63) af[256] = a4;
    WAIT_LGKM0;  // same-wave LDS: writes visible after lgkmcnt(0), no barrier needed
    if (l == 0) {
        const int tl = tlen[n];
        const float v1 = af[2 * tl];
        const float v2 = af[2 * tl - 1];
        float loss = -lse2(v1, v2) * LN2;
        // zero_infinity: keep only finite loss < 1e10 (NaN fails the < test too)
        if (!(loss < 1e10f) || !isfinite(loss)) loss = 0.0f;
        out[n] = loss;
    }
}

extern "C" void kernel_launch(void* const* d_in, const int* in_sizes, int n_in,
                              void* d_out, int out_size, void* d_ws, size_t ws_size,
                              hipStream_t stream) {
    const float* lp  = (const float*)d_in[0];
    const int*   tg  = (const int*)  d_in[1];
    const int*   il  = (const int*)  d_in[2];
    const int*   tl  = (const int*)  d_in[3];
    float*       out = (float*)d_out;
    const int N = in_sizes[2];  // 512
    ctc_fwd<<<N, 64, 0, stream>>>(lp, tg, il, tl, out, N);
}